// Round 2
// baseline (26203.137 us; speedup 1.0000x reference)
//
#include <hip/hip_runtime.h>
#include <hip/hip_bf16.h>

// Problem constants
#define B_   512
#define T_   256
#define F_   256
#define E_   256
#define H_   256
#define G4_  1024      // 4*H
#define K_   768       // H + E + F  (q | r | x)
#define NT   512       // threads per block (8 waves)

typedef __attribute__((ext_vector_type(8))) unsigned short ushort8v;
typedef __attribute__((ext_vector_type(4))) unsigned short ushort4v;
typedef __attribute__((ext_vector_type(2))) unsigned short ushort2v;

__device__ __forceinline__ float bf2f(unsigned int u) {
  union { unsigned int i; float f; } v; v.i = u << 16; return v.f;
}
__device__ __forceinline__ unsigned short f2bf(float f) {
  union { __hip_bfloat16 h; unsigned short u; } v;
  v.h = __float2bfloat16(f); return v.u;
}
__device__ __forceinline__ float sigm(float x) { return 1.f / (1.f + __expf(-x)); }
// tanh = 1 - 2/(exp(2x)+1); inf-safe at both ends, no NaN.
__device__ __forceinline__ float tanh_fast(float x) { return 1.f - 2.f / (1.f + __expf(2.f * x)); }

// ---------------- setup: fold weights, convert to bf16 ----------------
// Wcomb[n][k] (bf16): k<256 -> W_ih[n][k] + W_hh[n][k] (q part); else W_ih[n][k] (r|x part)
// Watt  (bf16) copy of W_att
// bcomb = b_ih + b_hh (f32)
__global__ void setup_kernel(const float* __restrict__ W_ih, const float* __restrict__ W_hh,
                             const float* __restrict__ b_ih, const float* __restrict__ b_hh,
                             const float* __restrict__ W_att,
                             unsigned short* __restrict__ Wcomb, unsigned short* __restrict__ Watt,
                             float* __restrict__ bcomb) {
  int idx = blockIdx.x * blockDim.x + threadIdx.x;
  if (idx < G4_ * K_) {
    int n = idx / K_, k = idx % K_;
    float v = W_ih[idx];
    if (k < H_) v += W_hh[n * H_ + k];
    Wcomb[idx] = f2bf(v);
    return;
  }
  idx -= G4_ * K_;
  if (idx < E_ * H_) { Watt[idx] = f2bf(W_att[idx]); return; }
  idx -= E_ * H_;
  if (idx < G4_) { bcomb[idx] = b_ih[idx] + b_hh[idx]; return; }
}

// ---------------- main: one block per molecule ----------------
__global__ __launch_bounds__(NT)
void mol_kernel(const float* __restrict__ features, const int* __restrict__ lengths,
                const unsigned short* __restrict__ Wcomb, const unsigned short* __restrict__ Watt,
                const float* __restrict__ W_embed, const float* __restrict__ bcomb,
                const float* __restrict__ Wfin, const float* __restrict__ bfin,
                const float* __restrict__ q0, const float* __restrict__ c0, const float* __restrict__ r0,
                float* __restrict__ out) {
  __shared__ unsigned short emb[T_][E_ + 2];   // 132096 B, bf16, +2 pad breaks bank alignment
  __shared__ float qrx[K_];                    // [q(256) | r(256) | x_t(256)] f32
  __shared__ float gates[G4_];
  __shared__ float cst[H_];
  __shared__ float qp[E_];
  __shared__ float esc[T_];
  __shared__ float wf[H_];
  __shared__ float red[8];
  __shared__ float fchunk[8][128];             // feat chunk (f-major), f32
  __shared__ float wechunk[8][E_];             // W_embed chunk (f-major), f32

  const int b   = blockIdx.x;
  const int tid = threadIdx.x;
  const int len = lengths[b];
  const float* featb = features + (size_t)b * T_ * F_;

  // ---- init state ----
  if (tid < H_) {
    qrx[tid] = q0[(size_t)b * H_ + tid];
    cst[tid] = c0[(size_t)b * H_ + tid];
    wf[tid]  = Wfin[tid];
  } else {
    int i = tid - H_;
    qrx[H_ + i] = r0[(size_t)b * E_ + i];
  }
  const float bfinal = bfin[0];

  // ---- embedding precompute into LDS: emb[t][e] = bf16(sum_f feat[t,f]*We[e,f]), rows t<len ----
  {
    const int tg = tid >> 4;   // 0..31 : owns t rows tg*4 .. tg*4+3 (within a 128-row half)
    const int eg = tid & 15;   // 0..15 : owns e cols eg*16 .. eg*16+15
    for (int th = 0; th < 2; ++th) {
      const int t0half = th * 128;
      if (t0half >= len) break;          // uniform
      float acc[4][16];
      #pragma unroll
      for (int i = 0; i < 4; ++i)
        #pragma unroll
        for (int j = 0; j < 16; ++j) acc[i][j] = 0.f;

      for (int fc = 0; fc < 32; ++fc) {  // f chunks of 8
        {  // stage features chunk: 1024 elems, 2/thread
          int l0 = tid * 2;
          int tloc = l0 >> 3, ff = l0 & 7;
          const float* src = featb + (size_t)(t0half + tloc) * F_ + fc * 8 + ff;
          float2 v = *reinterpret_cast<const float2*>(src);
          fchunk[ff][tloc] = v.x; fchunk[ff + 1][tloc] = v.y;
        }
        {  // stage W_embed chunk (f32 direct): 2048 elems, 4/thread
          int l0 = tid * 4;
          int e = l0 >> 3, ff = l0 & 7;
          const float* src = W_embed + (size_t)e * F_ + fc * 8 + ff;
          float4 v = *reinterpret_cast<const float4*>(src);
          wechunk[ff + 0][e] = v.x; wechunk[ff + 1][e] = v.y;
          wechunk[ff + 2][e] = v.z; wechunk[ff + 3][e] = v.w;
        }
        __syncthreads();
        #pragma unroll
        for (int ff = 0; ff < 8; ++ff) {
          float f0 = fchunk[ff][tg * 4 + 0];
          float f1 = fchunk[ff][tg * 4 + 1];
          float f2 = fchunk[ff][tg * 4 + 2];
          float f3 = fchunk[ff][tg * 4 + 3];
          #pragma unroll
          for (int j = 0; j < 16; ++j) {
            float w = wechunk[ff][eg * 16 + j];
            acc[0][j] += f0 * w; acc[1][j] += f1 * w;
            acc[2][j] += f2 * w; acc[3][j] += f3 * w;
          }
        }
        __syncthreads();
      }
      #pragma unroll
      for (int i = 0; i < 4; ++i) {
        int t = t0half + tg * 4 + i;
        #pragma unroll
        for (int j = 0; j < 16; ++j) emb[t][eg * 16 + j] = f2bf(acc[i][j]);
      }
    }
  }
  __syncthreads();

  // ---- recurrence over live steps ----
  for (int t = 0; t < len; ++t) {
    // x_t into qrx[512:768]
    if (tid < F_) qrx[512 + tid] = featb[(size_t)t * F_ + tid];
    __syncthreads();

    // gates matvec: thread computes rows tid and tid+512 over K=768 (bf16 weights, f32 acc)
    {
      const int n = tid;
      float a0 = bcomb[n], a1 = bcomb[n + 512];
      const ushort8v* w0 = reinterpret_cast<const ushort8v*>(Wcomb + (size_t)n * K_);
      const ushort8v* w1 = reinterpret_cast<const ushort8v*>(Wcomb + (size_t)(n + 512) * K_);
      #pragma unroll 4
      for (int k8 = 0; k8 < K_ / 8; ++k8) {
        ushort8v u0 = w0[k8];
        ushort8v u1 = w1[k8];
        const float* q8 = &qrx[k8 * 8];
        #pragma unroll
        for (int j = 0; j < 8; ++j) {
          float qv = q8[j];
          a0 += bf2f(u0[j]) * qv;
          a1 += bf2f(u1[j]) * qv;
        }
      }
      gates[n] = a0; gates[n + 512] = a1;
    }
    __syncthreads();

    // LSTM elementwise + output partial
    float po = 0.f;
    if (tid < H_) {
      float ig = gates[tid], fg = gates[H_ + tid], gg = gates[2 * H_ + tid], og = gates[3 * H_ + tid];
      float c  = cst[tid];
      float cn = sigm(fg) * c + sigm(ig) * tanh_fast(gg);
      float qn = sigm(og) * tanh_fast(cn);
      cst[tid] = cn;
      qrx[tid] = qn;
      po = fmaxf(qn, 0.f) * wf[tid];
    }
    #pragma unroll
    for (int s = 32; s >= 1; s >>= 1) po += __shfl_xor(po, s);
    if ((tid & 63) == 0) red[tid >> 6] = po;
    __syncthreads();
    if (tid == 0) {
      float s = red[0] + red[1] + red[2] + red[3] + red[4] + red[5] + red[6] + red[7];
      out[(size_t)b * T_ + t] = s + bfinal;
    }

    // qp[e] = sum_h Watt[e][h]*q[h]; 2 threads per e
    {
      const int e = tid >> 1, half = tid & 1;
      const ushort8v* wa = reinterpret_cast<const ushort8v*>(Watt + (size_t)e * H_ + half * 128);
      float acc = 0.f;
      #pragma unroll 4
      for (int k8 = 0; k8 < 16; ++k8) {
        ushort8v u = wa[k8];
        const float* q8 = &qrx[half * 128 + k8 * 8];
        #pragma unroll
        for (int j = 0; j < 8; ++j) acc += bf2f(u[j]) * q8[j];
      }
      acc += __shfl_xor(acc, 1);
      if (half == 0) qp[e] = acc;
    }
    __syncthreads();

    // scores e[tv] = emb[tv,:].qp  (2 threads per tv, dword-aligned ushort2 LDS reads)
    {
      const int tv = tid >> 1, half = tid & 1;
      if (tv < len) {
        const ushort2v* er = reinterpret_cast<const ushort2v*>(&emb[tv][half * 128]);
        const float* qh = &qp[half * 128];
        float acc = 0.f;
        #pragma unroll 8
        for (int k2 = 0; k2 < 64; ++k2) {
          ushort2v u = er[k2];
          acc += bf2f(u[0]) * qh[2 * k2] + bf2f(u[1]) * qh[2 * k2 + 1];
        }
        acc += __shfl_xor(acc, 1);
        if (half == 0) esc[tv] = acc;
      }
    }
    __syncthreads();

    // softmax over t' < len
    float lv = (tid < len) ? esc[tid] : -3.0e38f;
    #pragma unroll
    for (int s = 32; s >= 1; s >>= 1) lv = fmaxf(lv, __shfl_xor(lv, s));
    if ((tid & 63) == 0) red[tid >> 6] = lv;
    __syncthreads();
    const float m = fmaxf(fmaxf(fmaxf(red[0], red[1]), fmaxf(red[2], red[3])),
                          fmaxf(fmaxf(red[4], red[5]), fmaxf(red[6], red[7])));
    __syncthreads();                     // all reads of red done before re-writing it
    float pv = 0.f;
    if (tid < len) { pv = __expf(esc[tid] - m); esc[tid] = pv; }
    float sv = pv;
    #pragma unroll
    for (int s = 32; s >= 1; s >>= 1) sv += __shfl_xor(sv, s);
    if ((tid & 63) == 0) red[tid >> 6] = sv;
    __syncthreads();
    const float denom = red[0] + red[1] + red[2] + red[3] + red[4] + red[5] + red[6] + red[7];
    const float rinv = 1.f / denom;

    // r[e] = (sum_t p[t]*emb[t][e]) / denom  (2 threads per e, t split in halves)
    {
      const int e = tid >> 1, half = tid & 1;
      const int tlo = half * 128;
      const int thi = (len < tlo + 128) ? len : (tlo + 128);
      float acc = 0.f;
      for (int tt = tlo; tt < thi; ++tt) {
        acc += esc[tt] * bf2f(emb[tt][e]);
      }
      acc += __shfl_xor(acc, 1);
      if (half == 0) qrx[H_ + e] = acc * rinv;
    }
    __syncthreads();
  }

  // zero padded outputs
  for (int tt = len + tid; tt < T_; tt += NT) out[(size_t)b * T_ + tt] = 0.f;
}

extern "C" void kernel_launch(void* const* d_in, const int* in_sizes, int n_in,
                              void* d_out, int out_size, void* d_ws, size_t ws_size,
                              hipStream_t stream) {
  const float* features = (const float*)d_in[0];
  const int*   lengths  = (const int*)d_in[1];
  const float* W_embed  = (const float*)d_in[2];
  const float* W_ih     = (const float*)d_in[3];
  const float* b_ih     = (const float*)d_in[4];
  const float* W_hh     = (const float*)d_in[5];
  const float* b_hh     = (const float*)d_in[6];
  const float* W_att    = (const float*)d_in[7];
  const float* W_final  = (const float*)d_in[8];
  const float* b_final  = (const float*)d_in[9];
  const float* q0       = (const float*)d_in[10];
  const float* c0       = (const float*)d_in[11];
  const float* r0       = (const float*)d_in[12];
  float* out = (float*)d_out;

  char* ws = (char*)d_ws;
  unsigned short* Wcomb = (unsigned short*)(ws);                 // 1024*768*2 = 1572864 B
  unsigned short* Watt  = (unsigned short*)(ws + 1572864);       // 65536*2   =  131072 B
  float*          bcomb = (float*)(ws + 1572864 + 131072);       // 1024*4    =    4096 B

  const int setup_elems = G4_ * K_ + E_ * H_ + G4_;              // 852992
  setup_kernel<<<(setup_elems + 255) / 256, 256, 0, stream>>>(
      W_ih, W_hh, b_ih, b_hh, W_att, Wcomb, Watt, bcomb);

  mol_kernel<<<B_, NT, 0, stream>>>(
      features, lengths, Wcomb, Watt, W_embed, bcomb,
      W_final, b_final, q0, c0, r0, out);
}

// Round 3
// 5714.526 us; speedup vs baseline: 4.5854x; 4.5854x over previous
//
#include <hip/hip_runtime.h>
#include <hip/hip_bf16.h>

// Problem constants
#define B_   512
#define T_   256
#define F_   256
#define E_   256
#define H_   256
#define G4_  1024      // 4*H
#define K_   768       // H + E + F  (q | r | x)
#define NT   512       // threads per block (8 waves)
#define NBLK 256       // main kernel blocks (2 molecules each)

typedef __attribute__((ext_vector_type(8))) short short8;
typedef __attribute__((ext_vector_type(4))) float f32x4;
typedef __attribute__((ext_vector_type(2))) unsigned short ushort2v;
typedef __attribute__((ext_vector_type(8))) unsigned short ushort8v;

__device__ __forceinline__ float bf2f(unsigned int u) {
  union { unsigned int i; float f; } v; v.i = u << 16; return v.f;
}
__device__ __forceinline__ unsigned short f2bf(float f) {
  union { __hip_bfloat16 h; unsigned short u; } v;
  v.h = __float2bfloat16(f); return v.u;
}
__device__ __forceinline__ float sigm(float x) { return 1.f / (1.f + __expf(-x)); }
__device__ __forceinline__ float tanh_fast(float x) { return 1.f - 2.f / (1.f + __expf(2.f * x)); }

// ---------------- setup: pack weights into MFMA B-fragment streams ----------------
// Gates: Bg frag layout o = (((w*8+nt)*24+kt)*64+lane)*8+j
//        n = w*128 + nt*16 + (lane&15), k = kt*32 + (lane>>4)*8 + j
//        value = W_ih[n][k] + (k<256 ? W_hh[n][k] : 0)   [q|r|x column order]
// Att:   Ba frag layout o = (((w*2+nt)*8+kt)*64+lane)*8+j
//        n = w*32 + nt*16 + (lane&15), k = kt*32 + (lane>>4)*8 + j, value = W_att[n][k]
__global__ void setup_pack(const float* __restrict__ W_ih, const float* __restrict__ W_hh,
                           const float* __restrict__ b_ih, const float* __restrict__ b_hh,
                           const float* __restrict__ W_att,
                           unsigned short* __restrict__ Bg, unsigned short* __restrict__ Ba,
                           float* __restrict__ bcomb) {
  int idx = blockIdx.x * blockDim.x + threadIdx.x;
  if (idx < G4_ * K_) {
    int o = idx;
    int j = o & 7, lane = (o >> 3) & 63, r = o >> 9;
    int kt = r % 24, q2 = r / 24, nt = q2 & 7, w = q2 >> 3;
    int n = w * 128 + nt * 16 + (lane & 15);
    int k = kt * 32 + (lane >> 4) * 8 + j;
    float v = W_ih[n * K_ + k];
    if (k < H_) v += W_hh[n * H_ + k];
    Bg[o] = f2bf(v);
    return;
  }
  idx -= G4_ * K_;
  if (idx < E_ * H_) {
    int o = idx;
    int j = o & 7, lane = (o >> 3) & 63, r = o >> 9;
    int kt = r & 7, q2 = r >> 3, nt = q2 & 1, w = q2 >> 1;
    int n = w * 32 + nt * 16 + (lane & 15);
    int k = kt * 32 + (lane >> 4) * 8 + j;
    Ba[o] = f2bf(W_att[n * H_ + k]);
    return;
  }
  idx -= E_ * H_;
  if (idx < G4_) { bcomb[idx] = b_ih[idx] + b_hh[idx]; return; }
}

// ---------------- deterministic rank sort of lengths -> perm ----------------
__global__ void sort_kernel(const int* __restrict__ lengths, int* __restrict__ perm) {
  __shared__ int lens[B_];
  int tid = threadIdx.x;
  lens[tid] = lengths[tid];
  __syncthreads();
  int L = lens[tid];
  int pos = 0;
  for (int i = 0; i < B_; ++i) {
    int li = lens[i];
    pos += (li < L) || (li == L && i < tid);
  }
  perm[pos] = tid;
}

// ---------------- main: 256 blocks, 2 length-paired molecules each ----------------
__global__ __launch_bounds__(NT)
void mol2_kernel(const float* __restrict__ features, const int* __restrict__ lengths,
                 const int* __restrict__ perm,
                 const unsigned short* __restrict__ Bg, const unsigned short* __restrict__ Ba,
                 const float* __restrict__ bcomb, const float* __restrict__ W_embed,
                 const float* __restrict__ Wfin, const float* __restrict__ bfin,
                 const float* __restrict__ q0, const float* __restrict__ c0,
                 const float* __restrict__ r0, float* __restrict__ out) {
  __shared__ unsigned short emb[T_][E_ + 2];          // 132096 B
  __shared__ __align__(16) unsigned short qst[K_];    // [q|r|x] bf16
  __shared__ float cst[H_];
  __shared__ float gates_s[G4_];
  __shared__ float qp_s[E_];
  __shared__ float esc_s[T_];
  __shared__ float wf_s[H_];
  __shared__ float bcomb_s[G4_];
  __shared__ float sred[8];
  __shared__ float fchunk[8][128];
  __shared__ float wechunk[8][E_];

  const int tid  = threadIdx.x;
  const int w    = tid >> 6;
  const int lane = tid & 63;
  const float bfinal = bfin[0];

  if (tid < H_) wf_s[tid] = Wfin[tid];
  bcomb_s[tid] = bcomb[tid];
  bcomb_s[tid + 512] = bcomb[tid + 512];

  const short8* gb = reinterpret_cast<const short8*>(Bg) + (size_t)w * (8 * 24 * 64);
  const short8* ab = reinterpret_cast<const short8*>(Ba) + (size_t)w * (2 * 8 * 64);
  const short8* ap = reinterpret_cast<const short8*>(qst);

  for (int half = 0; half < 2; ++half) {
    const int b   = perm[half == 0 ? blockIdx.x : (B_ - 1 - blockIdx.x)];
    const int len = lengths[b];
    const float* featb = features + (size_t)b * T_ * F_;

    // ---- init state ----
    if (tid < H_) {
      qst[tid] = f2bf(q0[(size_t)b * H_ + tid]);
      cst[tid] = c0[(size_t)b * H_ + tid];
    } else {
      int i = tid - H_;
      qst[H_ + i] = f2bf(r0[(size_t)b * E_ + i]);
    }
    __syncthreads();

    // ---- embedding precompute into LDS (VALU, f32 acc) ----
    {
      const int tg = tid >> 4;   // 0..31
      const int eg = tid & 15;   // 0..15
      for (int th = 0; th < 2; ++th) {
        const int t0half = th * 128;
        if (t0half >= len) break;
        float acc[4][16];
        #pragma unroll
        for (int i = 0; i < 4; ++i)
          #pragma unroll
          for (int j = 0; j < 16; ++j) acc[i][j] = 0.f;

        for (int fc = 0; fc < 32; ++fc) {
          {
            int l0 = tid * 2;
            int tloc = l0 >> 3, ff = l0 & 7;
            const float* src = featb + (size_t)(t0half + tloc) * F_ + fc * 8 + ff;
            float2 v = *reinterpret_cast<const float2*>(src);
            fchunk[ff][tloc] = v.x; fchunk[ff + 1][tloc] = v.y;
          }
          {
            int l0 = tid * 4;
            int e = l0 >> 3, ff = l0 & 7;
            const float* src = W_embed + (size_t)e * F_ + fc * 8 + ff;
            float4 v = *reinterpret_cast<const float4*>(src);
            wechunk[ff + 0][e] = v.x; wechunk[ff + 1][e] = v.y;
            wechunk[ff + 2][e] = v.z; wechunk[ff + 3][e] = v.w;
          }
          __syncthreads();
          #pragma unroll
          for (int ff = 0; ff < 8; ++ff) {
            float f0 = fchunk[ff][tg * 4 + 0];
            float f1 = fchunk[ff][tg * 4 + 1];
            float f2 = fchunk[ff][tg * 4 + 2];
            float f3 = fchunk[ff][tg * 4 + 3];
            #pragma unroll
            for (int j = 0; j < 16; ++j) {
              float wv = wechunk[ff][eg * 16 + j];
              acc[0][j] += f0 * wv; acc[1][j] += f1 * wv;
              acc[2][j] += f2 * wv; acc[3][j] += f3 * wv;
            }
          }
          __syncthreads();
        }
        #pragma unroll
        for (int i = 0; i < 4; ++i) {
          int t = t0half + tg * 4 + i;
          #pragma unroll
          for (int j = 0; j < 16; ++j) emb[t][eg * 16 + j] = f2bf(acc[i][j]);
        }
      }
    }
    __syncthreads();

    // ---- recurrence ----
    for (int t = 0; t < len; ++t) {
      // x_t -> qst[512:768] (bf16)
      if (tid < F_) qst[512 + tid] = f2bf(featb[(size_t)t * F_ + tid]);
      __syncthreads();

      // gates = q_star @ Wcomb^T via MFMA; A = q_star replicated over 16 M rows
      {
        f32x4 acc[8];
        #pragma unroll
        for (int nt = 0; nt < 8; ++nt) acc[nt] = f32x4{0.f, 0.f, 0.f, 0.f};
        short8 b0[8], b1[8];
        #pragma unroll
        for (int nt = 0; nt < 8; ++nt) b0[nt] = gb[(nt * 24 + 0) * 64 + lane];
        for (int kt = 0; kt < 24; kt += 2) {
          #pragma unroll
          for (int nt = 0; nt < 8; ++nt) b1[nt] = gb[(nt * 24 + kt + 1) * 64 + lane];
          short8 a0 = ap[kt * 4 + (lane >> 4)];
          #pragma unroll
          for (int nt = 0; nt < 8; ++nt)
            acc[nt] = __builtin_amdgcn_mfma_f32_16x16x32_bf16(a0, b0[nt], acc[nt], 0, 0, 0);
          if (kt + 2 < 24) {
            #pragma unroll
            for (int nt = 0; nt < 8; ++nt) b0[nt] = gb[(nt * 24 + kt + 2) * 64 + lane];
          }
          short8 a1 = ap[(kt + 1) * 4 + (lane >> 4)];
          #pragma unroll
          for (int nt = 0; nt < 8; ++nt)
            acc[nt] = __builtin_amdgcn_mfma_f32_16x16x32_bf16(a1, b1[nt], acc[nt], 0, 0, 0);
        }
        if (lane < 16) {
          #pragma unroll
          for (int nt = 0; nt < 8; ++nt) {
            int n = w * 128 + nt * 16 + lane;
            gates_s[n] = acc[nt][0] + bcomb_s[n];
          }
        }
      }
      __syncthreads();

      // LSTM elementwise + out partial
      float po = 0.f;
      if (tid < H_) {
        float ig = gates_s[tid], fg = gates_s[H_ + tid];
        float gg = gates_s[2 * H_ + tid], og = gates_s[3 * H_ + tid];
        float c  = cst[tid];
        float cn = sigm(fg) * c + sigm(ig) * tanh_fast(gg);
        float qn = sigm(og) * tanh_fast(cn);
        cst[tid] = cn;
        qst[tid] = f2bf(qn);
        po = fmaxf(qn, 0.f) * wf_s[tid];
      }
      #pragma unroll
      for (int s = 32; s >= 1; s >>= 1) po += __shfl_xor(po, s);
      if ((tid & 63) == 0) sred[tid >> 6] = po;
      __syncthreads();
      if (tid == 0) {
        float s = sred[0] + sred[1] + sred[2] + sred[3] + sred[4] + sred[5] + sred[6] + sred[7];
        out[(size_t)b * T_ + t] = s + bfinal;
      }

      // qp = W_att @ q via MFMA (uses new q, fenced by the sync above)
      {
        f32x4 acc2[2];
        acc2[0] = f32x4{0.f, 0.f, 0.f, 0.f};
        acc2[1] = f32x4{0.f, 0.f, 0.f, 0.f};
        for (int kt = 0; kt < 8; ++kt) {
          short8 a = ap[kt * 4 + (lane >> 4)];
          #pragma unroll
          for (int nt = 0; nt < 2; ++nt) {
            short8 bfr = ab[(nt * 8 + kt) * 64 + lane];
            acc2[nt] = __builtin_amdgcn_mfma_f32_16x16x32_bf16(a, bfr, acc2[nt], 0, 0, 0);
          }
        }
        if (lane < 16) {
          qp_s[w * 32 + 0 * 16 + lane] = acc2[0][0];
          qp_s[w * 32 + 1 * 16 + lane] = acc2[1][0];
        }
      }
      __syncthreads();

      // scores esc[tv] = emb[tv,:] . qp  (2 threads per tv)
      {
        const int tv = tid >> 1, hf = tid & 1;
        if (tv < len) {
          const ushort2v* er = reinterpret_cast<const ushort2v*>(&emb[tv][hf * 128]);
          const float* qh = &qp_s[hf * 128];
          float acc = 0.f;
          #pragma unroll 8
          for (int k2 = 0; k2 < 64; ++k2) {
            ushort2v u = er[k2];
            acc += bf2f(u[0]) * qh[2 * k2] + bf2f(u[1]) * qh[2 * k2 + 1];
          }
          acc += __shfl_xor(acc, 1);
          if (hf == 0) esc_s[tv] = acc;
        }
      }
      __syncthreads();

      // softmax over t' < len
      float lv = (tid < len) ? esc_s[tid] : -3.0e38f;
      #pragma unroll
      for (int s = 32; s >= 1; s >>= 1) lv = fmaxf(lv, __shfl_xor(lv, s));
      if ((tid & 63) == 0) sred[tid >> 6] = lv;
      __syncthreads();
      const float m = fmaxf(fmaxf(fmaxf(sred[0], sred[1]), fmaxf(sred[2], sred[3])),
                            fmaxf(fmaxf(sred[4], sred[5]), fmaxf(sred[6], sred[7])));
      __syncthreads();
      float pv = 0.f;
      if (tid < len) { pv = __expf(esc_s[tid] - m); esc_s[tid] = pv; }
      float sv = pv;
      #pragma unroll
      for (int s = 32; s >= 1; s >>= 1) sv += __shfl_xor(sv, s);
      if ((tid & 63) == 0) sred[tid >> 6] = sv;
      __syncthreads();
      const float denom = sred[0] + sred[1] + sred[2] + sred[3] + sred[4] + sred[5] + sred[6] + sred[7];
      const float rinv = 1.f / denom;

      // r[e] = (sum_t p[t]*emb[t][e]) * rinv -> qst[256+e] (bf16)
      {
        const int e = tid >> 1, hf = tid & 1;
        const int tlo = hf * 128;
        const int thi = (len < tlo + 128) ? len : (tlo + 128);
        float acc = 0.f;
        for (int tt = tlo; tt < thi; ++tt) acc += esc_s[tt] * bf2f(emb[tt][e]);
        acc += __shfl_xor(acc, 1);
        if (hf == 0) qst[H_ + e] = f2bf(acc * rinv);
      }
      __syncthreads();
    }

    // zero padded outputs
    for (int tt = len + tid; tt < T_; tt += NT) out[(size_t)b * T_ + tt] = 0.f;
    __syncthreads();   // emb/qst reuse fence for second molecule
  }
}

extern "C" void kernel_launch(void* const* d_in, const int* in_sizes, int n_in,
                              void* d_out, int out_size, void* d_ws, size_t ws_size,
                              hipStream_t stream) {
  const float* features = (const float*)d_in[0];
  const int*   lengths  = (const int*)d_in[1];
  const float* W_embed  = (const float*)d_in[2];
  const float* W_ih     = (const float*)d_in[3];
  const float* b_ih     = (const float*)d_in[4];
  const float* W_hh     = (const float*)d_in[5];
  const float* b_hh     = (const float*)d_in[6];
  const float* W_att    = (const float*)d_in[7];
  const float* W_final  = (const float*)d_in[8];
  const float* b_final  = (const float*)d_in[9];
  const float* q0       = (const float*)d_in[10];
  const float* c0       = (const float*)d_in[11];
  const float* r0       = (const float*)d_in[12];
  float* out = (float*)d_out;

  char* ws = (char*)d_ws;
  unsigned short* Bg    = (unsigned short*)(ws);                       // 1572864 B
  unsigned short* Ba    = (unsigned short*)(ws + 1572864);             //  131072 B
  float*          bcomb = (float*)(ws + 1572864 + 131072);             //    4096 B
  int*            perm  = (int*)(ws + 1572864 + 131072 + 4096);        //    2048 B

  const int setup_elems = G4_ * K_ + E_ * H_ + G4_;                    // 852992
  setup_pack<<<(setup_elems + 255) / 256, 256, 0, stream>>>(
      W_ih, W_hh, b_ih, b_hh, W_att, Bg, Ba, bcomb);
  sort_kernel<<<1, B_, 0, stream>>>(lengths, perm);
  mol2_kernel<<<NBLK, NT, 0, stream>>>(
      features, lengths, perm, Bg, Ba, bcomb, W_embed,
      W_final, b_final, q0, c0, r0, out);
}